// Round 8
// baseline (849.082 us; speedup 1.0000x reference)
//
#include <hip/hip_runtime.h>
#include <hip/hip_bf16.h>

#define NEG_SLOPE 0.1f
#define D1 128
#define D2 256

__device__ __forceinline__ float leaky(float x) { return x >= 0.f ? x : NEG_SLOPE * x; }

__device__ __forceinline__ unsigned short f2bf(float x) {
    union { float f; unsigned int u; } v; v.f = x;
    unsigned int r = (v.u + 0x7FFFu + ((v.u >> 16) & 1u)) >> 16;   // RNE
    return (unsigned short)r;
}

// ---- stage 1: per-edge stats. Two fabric-atomic streams (measured floor:
// ~70us/stream; scope does NOT matter -- AGENT==whole GPU, memory-side RMW).
// rowstats8: packed u64 (count << 42 | fixed-point(abs_sum, 2^-24)), 8-way
// spread by XCC id purely to cut same-address contention.
// col_cnt: device atomic; returned value = edge's rank within its column.
__global__ void k_edge_stats(const int* __restrict__ row, const int* __restrict__ col,
                             const float* __restrict__ val,
                             unsigned long long* __restrict__ rowstats8,
                             int* __restrict__ col_cnt, int* __restrict__ rank, int E, int N)
{
    int e = blockIdx.x * blockDim.x + threadIdx.x;
    if (e >= E) return;
    // HW_REG_XCC_ID = 20, offset 0, size 32 -> simm16 = (31<<11)|20 = 63508
    unsigned xcc = (unsigned)__builtin_amdgcn_s_getreg(63508) & 7u;
    int r = row[e], c = col[e];
    float av = fabsf(val[e]);
    unsigned long long pk = (1ULL << 42) |
        (unsigned long long)__float2uint_rn(av * 16777216.0f);   // 2^24 fixed point
    __hip_atomic_fetch_add(&rowstats8[(size_t)xcc * N + r], pk,
                           __ATOMIC_RELAXED, __HIP_MEMORY_SCOPE_AGENT);
    rank[e] = atomicAdd(&col_cnt[c], 1);
}

// ---- stage 2: combine 8 row-stat copies; per-node abs_mean, deg, dinv, self pv ----
__global__ void k_node_stats(const unsigned long long* __restrict__ rowstats8,
                             float* __restrict__ dinv, float* __restrict__ pv_self, int N)
{
    int i = blockIdx.x * blockDim.x + threadIdx.x;
    if (i >= N) return;
    unsigned long long t = 0;
#pragma unroll
    for (int x = 0; x < 8; x++) t += rowstats8[(size_t)x * N + i];
    float c  = (float)(t >> 42);
    float as = (float)(t & ((1ULL << 42) - 1)) * (1.0f / 16777216.0f);
    float am = as / fmaxf(c, 1.0f);
    float deg = as + am;
    float di  = deg > 0.f ? rsqrtf(deg) : 0.f;
    dinv[i]    = di;
    pv_self[i] = am * di * di;
}

// ---- exclusive scan of col_cnt -> col_ptr ----
__global__ __launch_bounds__(256) void k_scan_local(const int* __restrict__ in, int* __restrict__ out,
                                                    int* __restrict__ partials, int n)
{
    __shared__ int s[256];
    int base = blockIdx.x * 2048 + threadIdx.x * 8;
    int v[8]; int sum = 0;
#pragma unroll
    for (int i = 0; i < 8; i++) { v[i] = (base + i < n) ? in[base + i] : 0; sum += v[i]; }
    s[threadIdx.x] = sum;
    __syncthreads();
    for (int off = 1; off < 256; off <<= 1) {
        int t = (threadIdx.x >= off) ? s[threadIdx.x - off] : 0;
        __syncthreads();
        s[threadIdx.x] += t;
        __syncthreads();
    }
    int excl = s[threadIdx.x] - sum;
#pragma unroll
    for (int i = 0; i < 8; i++) { if (base + i < n) { out[base + i] = excl; excl += v[i]; } }
    if (threadIdx.x == 255) partials[blockIdx.x] = s[255];
}

__global__ void k_scan_partials(int* __restrict__ partials, int nb, int* __restrict__ col_ptr,
                                int n, int total)
{
    if (threadIdx.x == 0) {
        int run = 0;
        for (int i = 0; i < nb; i++) { int t = partials[i]; partials[i] = run; run += t; }
        col_ptr[n] = total;
    }
}

__global__ void k_scan_add(int* __restrict__ out, const int* __restrict__ partials, int n)
{
    int i = blockIdx.x * blockDim.x + threadIdx.x;
    if (i < n) out[i] += partials[i >> 11];
}

// ---- scatter edges into dest-sorted CSR using precomputed ranks (no atomics) ----
__global__ void k_scatter(const int* __restrict__ row, const int* __restrict__ col,
                          const float* __restrict__ val, const float* __restrict__ dinv,
                          const int* __restrict__ col_ptr, const int* __restrict__ rank,
                          int2* __restrict__ srt_rp, int E)
{
    int e = blockIdx.x * blockDim.x + threadIdx.x;
    if (e >= E) return;
    int r = row[e], c = col[e];
    float p = val[e] * dinv[r] * dinv[c];
    int pos = col_ptr[c] + rank[e];
    srt_rp[pos] = make_int2(r, __float_as_int(p));
}

// ---- x1[i] = pv_self[i] + sum of pv over CSR range ----
__global__ void k_x1(const int* __restrict__ col_ptr, const int2* __restrict__ srt_rp,
                     const float* __restrict__ pv_self, float* __restrict__ x1, int N)
{
    int i = blockIdx.x * blockDim.x + threadIdx.x;
    if (i >= N) return;
    int s = col_ptr[i], e = col_ptr[i + 1];
    float acc = pv_self[i];
    for (int j = s; j < e; j++) acc += __int_as_float(srt_rp[j].y);
    x1[i] = acc;
}

// ---- pack edge-aligned (pv, x1[row]) stream for the scalar conv2 propagate ----
__global__ void k_gather_x1(const int2* __restrict__ srt_rp,
                            const float* __restrict__ x1, float2* __restrict__ px, int E)
{
    int j = blockIdx.x * blockDim.x + threadIdx.x;
    if (j >= E) return;
    int2 rp = srt_rp[j];
    px[j] = make_float2(__int_as_float(rp.y), x1[rp.x]);
}

// ---- conv2 propagate, scalar form:
// p2[i,d] = pv_self[i]*f_d(x1[i]) + sum_j pv_j * f_d(x1[r_j]),  f_d(s)=leaky(s*w1[d]+b1[d])
__global__ __launch_bounds__(256) void k_prop2(const int* __restrict__ col_ptr,
                                               const float2* __restrict__ px,
                                               const float* __restrict__ pv_self,
                                               const float* __restrict__ x1,
                                               const float* __restrict__ w1,
                                               const float* __restrict__ b1,
                                               float* __restrict__ p2, int N)
{
    int node = blockIdx.x * 2 + (threadIdx.x >> 7);
    int d = threadIdx.x & 127;
    if (node >= N) return;
    float wd = w1[d], bd = b1[d];
    float acc = pv_self[node] * leaky(fmaf(x1[node], wd, bd));
    int s = col_ptr[node], e = col_ptr[node + 1];
    for (int j = s; j < e; j++) {
        float2 t = px[j];
        acc += t.x * leaky(fmaf(t.y, wd, bd));
    }
    p2[(size_t)node * D1 + d] = acc;
}

// ---- fused conv2-GEMM + conv3-GEMM ----
// Per 64-node block:
//   Xs <- p2 tile (64x128, transposed [k][n])
//   for chunk c in 0..3 (64 h2-cols each):
//     Hs <- h2 chunk (64 m x 64 n) = leaky(p2 @ W2[c].T + x1*b2 + bias2)   (LDS only)
//     zacc += Hs.T @ W3[:, c].T  slice (k ascending -> bit-identical to 2-pass)
//   zb (bf16) <- zacc + b3
__global__ __launch_bounds__(256) void k_gemm_fused(const float* __restrict__ p2,
                                                    const float* __restrict__ w2,
                                                    const float* __restrict__ b2,
                                                    const float* __restrict__ bias2,
                                                    const float* __restrict__ x1,
                                                    const float* __restrict__ w3,
                                                    const float* __restrict__ b3,
                                                    unsigned short* __restrict__ zb, int N)
{
    __shared__ float Xs[128][64];     // p2 tile [k][n]
    __shared__ float Hs[64][68];      // h2 chunk [m_local][n], pad 68 for b128 align
    __shared__ float Ws[16][64];      // W2 k-chunk [k][m_local]
    __shared__ float W3s[16][132];    // W3 k-chunk [k][m], pad 132

    const int tid = threadIdx.x;
    const int nb  = blockIdx.x * 64;

    const int tc  = tid & 15, tr  = tid >> 4;   // phase A: 4x4 micro (64n x 64m)
    const int tc2 = tid & 31, tr2 = tid >> 5;   // phase B: 8x4 micro (64n x 128m)
    const int lr  = tid >> 2;                   // staging row 0..63
    const int lk  = (tid & 3) * 4;              // staging k 0,4,8,12
    const int m3  = tid >> 1;                   // W3 staging row 0..127
    const int k8  = (tid & 1) * 8;              // W3 staging k 0/8

    // load p2 tile transposed
    {
        const int node = nb + lr;
        const bool ok = node < N;
        const float* src = p2 + (size_t)node * D1;
#pragma unroll
        for (int q = 0; q < 8; q++) {
            int k = q * 16 + lk;
            float4 v = ok ? *(const float4*)(src + k) : make_float4(0.f, 0.f, 0.f, 0.f);
            Xs[k + 0][lr] = v.x; Xs[k + 1][lr] = v.y;
            Xs[k + 2][lr] = v.z; Xs[k + 3][lr] = v.w;
        }
    }

    float x1v[4];
#pragma unroll
    for (int ii = 0; ii < 4; ii++) {
        int node = nb + tr * 4 + ii;
        x1v[ii] = (node < N) ? x1[node] : 0.f;
    }

    float zacc[8][4] = {};

    for (int c = 0; c < 4; c++) {
        // ---- phase A: h2 chunk ----
        float hacc[4][4] = {};
        for (int k0 = 0; k0 < 128; k0 += 16) {
            float4 wv = *(const float4*)(w2 + (size_t)(c * 64 + lr) * D1 + k0 + lk);
            __syncthreads();
            Ws[lk + 0][lr] = wv.x; Ws[lk + 1][lr] = wv.y;
            Ws[lk + 2][lr] = wv.z; Ws[lk + 3][lr] = wv.w;
            __syncthreads();
#pragma unroll
            for (int k = 0; k < 16; k++) {
                float4 a = *(const float4*)&Xs[k0 + k][tr * 4];
                float4 b = *(const float4*)&Ws[k][tc * 4];
                hacc[0][0] += a.x * b.x; hacc[0][1] += a.x * b.y; hacc[0][2] += a.x * b.z; hacc[0][3] += a.x * b.w;
                hacc[1][0] += a.y * b.x; hacc[1][1] += a.y * b.y; hacc[1][2] += a.y * b.z; hacc[1][3] += a.y * b.w;
                hacc[2][0] += a.z * b.x; hacc[2][1] += a.z * b.y; hacc[2][2] += a.z * b.z; hacc[2][3] += a.z * b.w;
                hacc[3][0] += a.w * b.x; hacc[3][1] += a.w * b.y; hacc[3][2] += a.w * b.z; hacc[3][3] += a.w * b.w;
            }
        }
        // epilogue -> Hs[m_local][n]
        __syncthreads();
#pragma unroll
        for (int jj = 0; jj < 4; jj++) {
            int m = c * 64 + tc * 4 + jj;
            float bm = b2[m], cm = bias2[m];
            float4 h4;
            h4.x = leaky(hacc[0][jj] + x1v[0] * bm + cm);
            h4.y = leaky(hacc[1][jj] + x1v[1] * bm + cm);
            h4.z = leaky(hacc[2][jj] + x1v[2] * bm + cm);
            h4.w = leaky(hacc[3][jj] + x1v[3] * bm + cm);
            *(float4*)&Hs[tc * 4 + jj][tr * 4] = h4;
        }
        // ---- phase B: zacc += Hs.T @ W3[:, c*64..].T ----
        for (int k0 = 0; k0 < 64; k0 += 16) {
            float4 w3a = *(const float4*)(w3 + (size_t)m3 * D2 + c * 64 + k0 + k8);
            float4 w3b = *(const float4*)(w3 + (size_t)m3 * D2 + c * 64 + k0 + k8 + 4);
            __syncthreads();
            W3s[k8 + 0][m3] = w3a.x; W3s[k8 + 1][m3] = w3a.y;
            W3s[k8 + 2][m3] = w3a.z; W3s[k8 + 3][m3] = w3a.w;
            W3s[k8 + 4][m3] = w3b.x; W3s[k8 + 5][m3] = w3b.y;
            W3s[k8 + 6][m3] = w3b.z; W3s[k8 + 7][m3] = w3b.w;
            __syncthreads();
#pragma unroll
            for (int k = 0; k < 16; k++) {
                float4 a0 = *(const float4*)&Hs[k0 + k][tr2 * 8];
                float4 a1 = *(const float4*)&Hs[k0 + k][tr2 * 8 + 4];
                float4 b  = *(const float4*)&W3s[k][tc2 * 4];
                zacc[0][0] += a0.x * b.x; zacc[0][1] += a0.x * b.y; zacc[0][2] += a0.x * b.z; zacc[0][3] += a0.x * b.w;
                zacc[1][0] += a0.y * b.x; zacc[1][1] += a0.y * b.y; zacc[1][2] += a0.y * b.z; zacc[1][3] += a0.y * b.w;
                zacc[2][0] += a0.z * b.x; zacc[2][1] += a0.z * b.y; zacc[2][2] += a0.z * b.z; zacc[2][3] += a0.z * b.w;
                zacc[3][0] += a0.w * b.x; zacc[3][1] += a0.w * b.y; zacc[3][2] += a0.w * b.z; zacc[3][3] += a0.w * b.w;
                zacc[4][0] += a1.x * b.x; zacc[4][1] += a1.x * b.y; zacc[4][2] += a1.x * b.z; zacc[4][3] += a1.x * b.w;
                zacc[5][0] += a1.y * b.x; zacc[5][1] += a1.y * b.y; zacc[5][2] += a1.y * b.z; zacc[5][3] += a1.y * b.w;
                zacc[6][0] += a1.z * b.x; zacc[6][1] += a1.z * b.y; zacc[6][2] += a1.z * b.z; zacc[6][3] += a1.z * b.w;
                zacc[7][0] += a1.w * b.x; zacc[7][1] += a1.w * b.y; zacc[7][2] += a1.w * b.z; zacc[7][3] += a1.w * b.w;
            }
        }
    }

    // ---- z epilogue: + b3, bf16, store ----
    float b3v[4];
#pragma unroll
    for (int j = 0; j < 4; j++) b3v[j] = b3[tc2 * 4 + j];
#pragma unroll
    for (int i = 0; i < 8; i++) {
        int node = nb + tr2 * 8 + i;
        if (node >= N) continue;
        ushort4 s4;
        s4.x = f2bf(zacc[i][0] + b3v[0]);
        s4.y = f2bf(zacc[i][1] + b3v[1]);
        s4.z = f2bf(zacc[i][2] + b3v[2]);
        s4.w = f2bf(zacc[i][3] + b3v[3]);
        *(ushort4*)(zb + (size_t)node * D1 + tc2 * 4) = s4;
    }
}

// ---- conv3 gather propagate over bf16 z, one wave per node, 2 dims per lane ----
__global__ __launch_bounds__(256) void k_prop3_bf16(const int* __restrict__ col_ptr,
                                                    const int2* __restrict__ srt_rp,
                                                    const float* __restrict__ pv_self,
                                                    const unsigned int* __restrict__ zb,
                                                    const float* __restrict__ bias3,
                                                    float* __restrict__ out, int N)
{
    int node = blockIdx.x * 4 + (threadIdx.x >> 6);
    int lane = threadIdx.x & 63;
    if (node >= N) return;

    unsigned int us = zb[(size_t)node * 64 + lane];
    float ps = pv_self[node];
    float acc0 = ps * __uint_as_float(us << 16);
    float acc1 = ps * __uint_as_float(us & 0xFFFF0000u);

    int j = col_ptr[node], e = col_ptr[node + 1];
    for (; j + 3 < e; j += 4) {
        int2 rp0 = srt_rp[j];
        int2 rp1 = srt_rp[j + 1];
        int2 rp2 = srt_rp[j + 2];
        int2 rp3 = srt_rp[j + 3];
        unsigned int u0 = zb[(size_t)rp0.x * 64 + lane];
        unsigned int u1 = zb[(size_t)rp1.x * 64 + lane];
        unsigned int u2 = zb[(size_t)rp2.x * 64 + lane];
        unsigned int u3 = zb[(size_t)rp3.x * 64 + lane];
        float p0 = __int_as_float(rp0.y), p1 = __int_as_float(rp1.y);
        float p2 = __int_as_float(rp2.y), p3 = __int_as_float(rp3.y);
        acc0 += p0 * __uint_as_float(u0 << 16);
        acc1 += p0 * __uint_as_float(u0 & 0xFFFF0000u);
        acc0 += p1 * __uint_as_float(u1 << 16);
        acc1 += p1 * __uint_as_float(u1 & 0xFFFF0000u);
        acc0 += p2 * __uint_as_float(u2 << 16);
        acc1 += p2 * __uint_as_float(u2 & 0xFFFF0000u);
        acc0 += p3 * __uint_as_float(u3 << 16);
        acc1 += p3 * __uint_as_float(u3 & 0xFFFF0000u);
    }
    for (; j < e; j++) {
        int2 rp = srt_rp[j];
        unsigned int u = zb[(size_t)rp.x * 64 + lane];
        float p = __int_as_float(rp.y);
        acc0 += p * __uint_as_float(u << 16);
        acc1 += p * __uint_as_float(u & 0xFFFF0000u);
    }

    float2 b = *(const float2*)&bias3[lane * 2];
    float2 o = make_float2(leaky(acc0 + b.x), leaky(acc1 + b.y));
    *(float2*)&out[(size_t)node * D1 + lane * 2] = o;
}

extern "C" void kernel_launch(void* const* d_in, const int* in_sizes, int n_in,
                              void* d_out, int out_size, void* d_ws, size_t ws_size,
                              hipStream_t stream)
{
    const int* ei       = (const int*)d_in[0];     // (2,E) int32
    const float* val    = (const float*)d_in[1];   // (E,)
    const float* w1     = (const float*)d_in[3];   // (128,1)
    const float* b1     = (const float*)d_in[4];   // (128,)
    const float* w2     = (const float*)d_in[5];   // (256,128)
    const float* b2     = (const float*)d_in[6];   // (256,)
    const float* bias2  = (const float*)d_in[7];   // (256,)
    const float* w3     = (const float*)d_in[8];   // (128,256)
    const float* b3     = (const float*)d_in[9];   // (128,)
    const float* bias3  = (const float*)d_in[10];  // (128,)
    float* out = (float*)d_out;

    const int E = in_sizes[1];
    const int N = out_size / D1;
    const int* row = ei;
    const int* col = ei + E;

    // workspace layout
    unsigned long long* rowstats8 = (unsigned long long*)d_ws;       // 8*N u64 (zeroed)
    int*   col_cnt = (int*)(rowstats8 + (size_t)8 * N);              // N (zeroed)
    float* dinv    = (float*)(col_cnt + N);                          // N
    float* pv_self = dinv + N;                                       // N
    float* x1      = pv_self + N;                                    // N
    int*   col_ptr = (int*)(x1 + N);                                 // N+1
    int*   partials= col_ptr + N + 8;                                // 64
    int*   rank    = partials + 64;                                  // E
    int2*  srt_rp  = (int2*)(rank + E);                              // E int2
    float2* px     = (float2*)(srt_rp + (size_t)E);                  // E float2
    float* p2      = (float*)(px + (size_t)E);                       // N*128 fp32
    unsigned short* zb = (unsigned short*)(p2 + (size_t)N * D1);     // N*128 bf16

    hipMemsetAsync(d_ws, 0, (size_t)8 * N * 8 + (size_t)N * 4, stream);

    const int B = 256;
    const int scan_blocks = (N + 2047) / 2048;

    k_edge_stats<<<(E + B - 1) / B, B, 0, stream>>>(row, col, val, rowstats8, col_cnt, rank, E, N);
    k_node_stats<<<(N + B - 1) / B, B, 0, stream>>>(rowstats8, dinv, pv_self, N);

    k_scan_local<<<scan_blocks, 256, 0, stream>>>(col_cnt, col_ptr, partials, N);
    k_scan_partials<<<1, 64, 0, stream>>>(partials, scan_blocks, col_ptr, N, E);
    k_scan_add<<<(N + B - 1) / B, B, 0, stream>>>(col_ptr, partials, N);

    k_scatter<<<(E + B - 1) / B, B, 0, stream>>>(row, col, val, dinv, col_ptr, rank, srt_rp, E);
    k_x1<<<(N + B - 1) / B, B, 0, stream>>>(col_ptr, srt_rp, pv_self, x1, N);
    k_gather_x1<<<(E + B - 1) / B, B, 0, stream>>>(srt_rp, x1, px, E);

    // conv2: scalar-form propagate, then fused GEMM (conv2-lin + conv3-lin, h2 in LDS)
    k_prop2<<<(N + 1) / 2, 256, 0, stream>>>(col_ptr, px, pv_self, x1, w1, b1, p2, N);
    k_gemm_fused<<<(N + 63) / 64, 256, 0, stream>>>(p2, w2, b2, bias2, x1, w3, b3, zb, N);

    // conv3: bf16 gather propagate + fused bias3/leaky
    k_prop3_bf16<<<(N + 3) / 4, 256, 0, stream>>>(col_ptr, srt_rp, pv_self,
                                                  (const unsigned int*)zb, bias3, out, N);
}